// Round 1
// baseline (85.970 us; speedup 1.0000x reference)
//
#include <hip/hip_runtime.h>
#include <float.h>

#define BATCH 16
#define CH 3
#define HH 256
#define WW 256
#define TW 32
#define TH 32
#define HALO 2
#define TILE_W (TW + 2 * HALO)   // 36
#define TILE_H (TH + 2 * HALO)   // 36
#define BIGV 1e30f

__global__ void zero_out_kernel(float* out) {
    if (threadIdx.x == 0) out[0] = 0.0f;
}

__global__ __launch_bounds__(256) void nnloss_kernel(
    const float* __restrict__ pred,
    const float* __restrict__ gt,
    float* __restrict__ out)
{
    // gt tile with halo; 3 channels packed into float4 (w unused)
    __shared__ float4 tile[TILE_H * TILE_W];   // 36*36*16 = 20736 B
    __shared__ float warp_sums[4];

    const int tid = threadIdx.x;
    const int w0 = blockIdx.x * TW;
    const int h0 = blockIdx.y * TH;
    const int b  = blockIdx.z;

    const size_t plane = (size_t)HH * WW;
    const size_t gbase = (size_t)b * CH * plane;

    // ---- stage gt tile (channels packed) ----
    for (int idx = tid; idx < TILE_H * TILE_W; idx += 256) {
        const int r   = idx / TILE_W;
        const int col = idx - r * TILE_W;
        const int gh = h0 + r - HALO;
        const int gw = w0 + col - HALO;
        float4 v = make_float4(BIGV, BIGV, BIGV, 0.0f);
        if ((unsigned)gh < HH && (unsigned)gw < WW) {
            const size_t o = gbase + (size_t)gh * WW + gw;
            v.x = gt[o];
            v.y = gt[o + plane];
            v.z = gt[o + 2 * plane];
        }
        tile[idx] = v;
    }
    __syncthreads();

    // ---- compute: each thread does a 4-row vertical strip ----
    const int tx = tid & 31;        // 0..31 (output col within tile)
    const int ty = tid >> 5;        // 0..7  -> rows ty*4 .. ty*4+3
    const int row_base = ty * 4;

    float p0[4], p1[4], p2[4];
    float m[4];
    #pragma unroll
    for (int o = 0; o < 4; ++o) {
        const int gh = h0 + row_base + o;
        const size_t off = gbase + (size_t)gh * WW + (w0 + tx);
        p0[o] = pred[off];
        p1[o] = pred[off + plane];
        p2[o] = pred[off + 2 * plane];
        m[o] = FLT_MAX;
    }

    // gt rows needed: row_base .. row_base+7 (tile coords); each read once,
    // reused for all output rows o with 0 <= k-o <= 4
    #pragma unroll
    for (int k = 0; k < 8; ++k) {
        const int tr = row_base + k;
        #pragma unroll
        for (int dj = 0; dj < 5; ++dj) {
            const float4 g = tile[tr * TILE_W + tx + dj];
            #pragma unroll
            for (int o = 0; o < 4; ++o) {
                if (k - o >= 0 && k - o <= 4) {
                    const float s = fabsf(g.x - p0[o])
                                  + fabsf(g.y - p1[o])
                                  + fabsf(g.z - p2[o]);
                    m[o] = fminf(m[o], s);
                }
            }
        }
    }

    float local = m[0] + m[1] + m[2] + m[3];

    // ---- block reduction ----
    #pragma unroll
    for (int off = 32; off > 0; off >>= 1)
        local += __shfl_down(local, off, 64);
    if ((tid & 63) == 0) warp_sums[tid >> 6] = local;
    __syncthreads();
    if (tid == 0) {
        atomicAdd(out, warp_sums[0] + warp_sums[1] + warp_sums[2] + warp_sums[3]);
    }
}

extern "C" void kernel_launch(void* const* d_in, const int* in_sizes, int n_in,
                              void* d_out, int out_size, void* d_ws, size_t ws_size,
                              hipStream_t stream) {
    const float* pred = (const float*)d_in[0];
    const float* gt   = (const float*)d_in[1];
    float* out = (float*)d_out;

    zero_out_kernel<<<1, 64, 0, stream>>>(out);

    dim3 grid(WW / TW, HH / TH, BATCH);   // 8 x 8 x 16 = 1024 blocks
    nnloss_kernel<<<grid, 256, 0, stream>>>(pred, gt, out);
}

// Round 2
// 75.723 us; speedup vs baseline: 1.1353x; 1.1353x over previous
//
#include <hip/hip_runtime.h>
#include <float.h>

#define BATCH 16
#define CH 3
#define HH 256
#define WW 256
#define TW 32
#define TH 32
#define HALO 2
#define TILE_W (TW + 2 * HALO)   // 36
#define TILE_H (TH + 2 * HALO)   // 36
#define BIGV 1e30f
#define NBLOCKS ((WW / TW) * (HH / TH) * BATCH)   // 1024

__global__ __launch_bounds__(256) void nnloss_kernel(
    const float* __restrict__ pred,
    const float* __restrict__ gt,
    float* __restrict__ partials)
{
    // gt tile with halo; 3 channels packed into float4 (w unused)
    __shared__ float4 tile[TILE_H * TILE_W];   // 36*36*16 = 20736 B
    __shared__ float warp_sums[4];

    const int tid = threadIdx.x;
    const int w0 = blockIdx.x * TW;
    const int h0 = blockIdx.y * TH;
    const int b  = blockIdx.z;

    const size_t plane = (size_t)HH * WW;
    const size_t gbase = (size_t)b * CH * plane;

    // ---- stage gt tile (channels packed) ----
    for (int idx = tid; idx < TILE_H * TILE_W; idx += 256) {
        const int r   = idx / TILE_W;
        const int col = idx - r * TILE_W;
        const int gh = h0 + r - HALO;
        const int gw = w0 + col - HALO;
        float4 v = make_float4(BIGV, BIGV, BIGV, 0.0f);
        if ((unsigned)gh < HH && (unsigned)gw < WW) {
            const size_t o = gbase + (size_t)gh * WW + gw;
            v.x = gt[o];
            v.y = gt[o + plane];
            v.z = gt[o + 2 * plane];
        }
        tile[idx] = v;
    }
    __syncthreads();

    // ---- compute: each thread does a 4-row vertical strip ----
    const int tx = tid & 31;        // 0..31 (output col within tile)
    const int ty = tid >> 5;        // 0..7  -> rows ty*4 .. ty*4+3
    const int row_base = ty * 4;

    float p0[4], p1[4], p2[4];
    float m[4];
    #pragma unroll
    for (int o = 0; o < 4; ++o) {
        const int gh = h0 + row_base + o;
        const size_t off = gbase + (size_t)gh * WW + (w0 + tx);
        p0[o] = pred[off];
        p1[o] = pred[off + plane];
        p2[o] = pred[off + 2 * plane];
        m[o] = FLT_MAX;
    }

    // gt rows needed: row_base .. row_base+7 (tile coords); each read once,
    // reused for all output rows o with 0 <= k-o <= 4
    #pragma unroll
    for (int k = 0; k < 8; ++k) {
        const int tr = row_base + k;
        #pragma unroll
        for (int dj = 0; dj < 5; ++dj) {
            const float4 g = tile[tr * TILE_W + tx + dj];
            #pragma unroll
            for (int o = 0; o < 4; ++o) {
                if (k - o >= 0 && k - o <= 4) {
                    const float s = fabsf(g.x - p0[o])
                                  + fabsf(g.y - p1[o])
                                  + fabsf(g.z - p2[o]);
                    m[o] = fminf(m[o], s);
                }
            }
        }
    }

    float local = m[0] + m[1] + m[2] + m[3];

    // ---- block reduction -> one partial per block (no atomics) ----
    #pragma unroll
    for (int off = 32; off > 0; off >>= 1)
        local += __shfl_down(local, off, 64);
    if ((tid & 63) == 0) warp_sums[tid >> 6] = local;
    __syncthreads();
    if (tid == 0) {
        const int bid = (blockIdx.z * gridDim.y + blockIdx.y) * gridDim.x + blockIdx.x;
        partials[bid] = warp_sums[0] + warp_sums[1] + warp_sums[2] + warp_sums[3];
    }
}

__global__ __launch_bounds__(256) void reduce_kernel(
    const float* __restrict__ partials, float* __restrict__ out)
{
    __shared__ float warp_sums[4];
    const int tid = threadIdx.x;
    float local = 0.0f;
    #pragma unroll
    for (int i = 0; i < NBLOCKS / 256; ++i)
        local += partials[i * 256 + tid];
    #pragma unroll
    for (int off = 32; off > 0; off >>= 1)
        local += __shfl_down(local, off, 64);
    if ((tid & 63) == 0) warp_sums[tid >> 6] = local;
    __syncthreads();
    if (tid == 0)
        out[0] = warp_sums[0] + warp_sums[1] + warp_sums[2] + warp_sums[3];
}

extern "C" void kernel_launch(void* const* d_in, const int* in_sizes, int n_in,
                              void* d_out, int out_size, void* d_ws, size_t ws_size,
                              hipStream_t stream) {
    const float* pred = (const float*)d_in[0];
    const float* gt   = (const float*)d_in[1];
    float* out = (float*)d_out;
    float* partials = (float*)d_ws;   // 1024 floats = 4 KB of the workspace

    dim3 grid(WW / TW, HH / TH, BATCH);   // 8 x 8 x 16 = 1024 blocks
    nnloss_kernel<<<grid, 256, 0, stream>>>(pred, gt, partials);
    reduce_kernel<<<1, 256, 0, stream>>>(partials, out);
}